// Round 1
// baseline (716.311 us; speedup 1.0000x reference)
//
#include <hip/hip_runtime.h>

#define NBATCH 16
#define CH 512
#define HID 32
#define KTOP 153
#define SP 4096
#define NELEM (NBATCH*CH*SP)   // 33554432

typedef __bf16 bf16x8 __attribute__((ext_vector_type(8)));
typedef float f32x16 __attribute__((ext_vector_type(16)));

__device__ __forceinline__ unsigned short f2bf(float f) {
    union { float f; unsigned u; } v; v.f = f;
    unsigned r = v.u + 0x7FFFu + ((v.u >> 16) & 1u);   // RNE
    return (unsigned short)(r >> 16);
}

__device__ __forceinline__ void gld_lds16(const void* g, void* l) {
    __builtin_amdgcn_global_load_lds(
        (__attribute__((address_space(1))) unsigned int*)g,
        (__attribute__((address_space(3))) unsigned int*)l, 16, 0, 0);
}

// ---------------------------------------------------------------------------
// K1: per-(b,ch) spatial partial sums (fp32, deterministic) + transpose x to
// channel-major bf16 xb[b][s][k] (so GEMM B granules = 8 bf16 along k, 16B).
// grid (64 s-blocks, 8 ch-blocks, 32 = b*2+branch), block 256.
// ---------------------------------------------------------------------------
__global__ __launch_bounds__(256) void k1_reduce_transpose(
    const float* __restrict__ xt, const float* __restrict__ xc,
    unsigned short* __restrict__ xbt, unsigned short* __restrict__ xbc,
    float* __restrict__ psum)
{
    int sb = blockIdx.x, chb = blockIdx.y, bz = blockIdx.z;
    int b = bz >> 1, br = bz & 1;
    const float* x = br ? xc : xt;
    unsigned short* xb = br ? xbc : xbt;
    int t = threadIdx.x, lane = t & 63, w = t >> 6;
    int s0 = sb * 64, ch0 = chb * 64;

    __shared__ unsigned short T[64 * 68];   // [s][ch], pad row 68 shorts

    float vals[16];
    const float* xbase = x + (size_t)b * CH * SP + s0 + lane;
    #pragma unroll
    for (int it = 0; it < 4; ++it)
        #pragma unroll
        for (int i = 0; i < 4; ++i) {
            int chl = w * 4 + i + 16 * it;
            vals[it * 4 + i] = xbase[(size_t)(ch0 + chl) * SP];
        }

    // transposed bf16 write to LDS (b64 stores, 2-way conflicts = free)
    #pragma unroll
    for (int it = 0; it < 4; ++it) {
        int chl = w * 4 + 16 * it;
        ushort4 p;
        p.x = f2bf(vals[it * 4 + 0]); p.y = f2bf(vals[it * 4 + 1]);
        p.z = f2bf(vals[it * 4 + 2]); p.w = f2bf(vals[it * 4 + 3]);
        *(ushort4*)&T[lane * 68 + chl] = p;
    }

    // wave tree-reduce over the 64 spatial positions (lane == s)
    #pragma unroll
    for (int k = 0; k < 16; ++k) {
        float v = vals[k];
        #pragma unroll
        for (int off = 32; off; off >>= 1) v += __shfl_xor(v, off, 64);
        vals[k] = v;
    }
    if (lane < 16) {   // all lanes hold identical reduced values; spread writes
        int it = lane >> 2, i = lane & 3;
        int chl = w * 4 + i + 16 * it;
        psum[(((size_t)(br * 16 + b)) * CH + ch0 + chl) * 64 + sb] = vals[lane];
    }

    __syncthreads();
    // write xb[b][s0+s][ch0..ch0+63] as 8B chunks, coalesced
    size_t orow = (size_t)b * SP + s0;
    #pragma unroll
    for (int q = 0; q < 4; ++q) {
        int gid = q * 256 + t;
        int sl = gid >> 4;
        int c4 = (gid & 15) * 4;
        ushort4 d = *(const ushort4*)&T[sl * 68 + c4];
        *(ushort4*)&xb[(orow + sl) * CH + ch0 + c4] = d;
    }
}

// ---------------------------------------------------------------------------
// K2a: finish means, SE MLP (fp32), sigmoid, exact top-153 mask (t branch).
// grid (16 b, 2 branch), block 512.
// ---------------------------------------------------------------------------
__global__ __launch_bounds__(512) void k2_se(
    const float* __restrict__ psum,
    const float* __restrict__ w1t, const float* __restrict__ b1t,
    const float* __restrict__ w2t, const float* __restrict__ b2t,
    const float* __restrict__ w1c, const float* __restrict__ b1c,
    const float* __restrict__ w2c, const float* __restrict__ b2c,
    float* __restrict__ sAt, float* __restrict__ sBt, float* __restrict__ attc)
{
    int b = blockIdx.x, br = blockIdx.y;
    int t = threadIdx.x;
    __shared__ float satt[512];
    __shared__ float sh[32];
    __shared__ float sval[512];

    const float* pr = psum + (((size_t)(br * 16 + b)) * CH + t) * 64;
    float s = 0.f;
    #pragma unroll
    for (int j = 0; j < 64; ++j) s += pr[j];
    satt[t] = s * (1.0f / 4096.0f);
    __syncthreads();

    const float* w1 = br ? w1c : w1t; const float* b1 = br ? b1c : b1t;
    const float* w2 = br ? w2c : w2t; const float* b2 = br ? b2c : b2t;

    if (t < HID) {
        float h = b1[t];
        for (int i = 0; i < CH; ++i) h += satt[i] * w1[i * HID + t];
        sh[t] = fmaxf(h, 0.0f);
    }
    __syncthreads();
    float z = b2[t];
    #pragma unroll
    for (int j = 0; j < HID; ++j) z += sh[j] * w2[j * CH + t];
    float a = 1.0f / (1.0f + expf(-z));

    if (br == 0) {
        sval[t] = a;
        __syncthreads();
        int cnt = 0;
        for (int j = 0; j < CH; ++j) {
            float o = sval[j];
            cnt += (o > a) || (o == a && j < t);   // matches top_k tie order
        }
        sAt[b * CH + t] = a;
        sBt[b * CH + t] = (cnt < KTOP) ? 1.0f : 0.0f;
    } else {
        attc[b * CH + t] = a;
    }
}

// ---------------------------------------------------------------------------
// K2b: softmax rows of cross_att -> bf16 W, written PRE-SWIZZLED into MFMA
// A-fragment granule order: granule(m,k8): kb=k>>5, ks=(k>>4)&1, hi=(k>>3)&1,
// pos = ((kb*16 + (m>>5))*2 + ks)*64 + hi*32 + (m&31), 16B each.
// grid 512 rows, block 64.
// ---------------------------------------------------------------------------
__global__ __launch_bounds__(64) void k2_softmax(
    const float* __restrict__ ca, unsigned short* __restrict__ wswz)
{
    int trow = blockIdx.x;
    int lane = threadIdx.x;
    const float* row = ca + (size_t)trow * CH;
    float v[8];
    #pragma unroll
    for (int i = 0; i < 8; ++i) v[i] = row[lane * 8 + i];
    float m = v[0];
    #pragma unroll
    for (int i = 1; i < 8; ++i) m = fmaxf(m, v[i]);
    #pragma unroll
    for (int off = 32; off; off >>= 1) m = fmaxf(m, __shfl_xor(m, off, 64));
    float s = 0.f;
    #pragma unroll
    for (int i = 0; i < 8; ++i) { v[i] = expf(v[i] - m); s += v[i]; }
    #pragma unroll
    for (int off = 32; off; off >>= 1) s += __shfl_xor(s, off, 64);
    float inv = 1.0f / s;

    int k = lane * 8;
    int kb = k >> 5, ks = (k >> 4) & 1, hi = (k >> 3) & 1;
    int p = ((kb * 16 + (trow >> 5)) * 2 + ks) * 64 + hi * 32 + (trow & 31);
    unsigned short* dst = wswz + (size_t)p * 8;
    ushort4 lo, hm;
    lo.x = f2bf(v[0] * inv); lo.y = f2bf(v[1] * inv);
    lo.z = f2bf(v[2] * inv); lo.w = f2bf(v[3] * inv);
    hm.x = f2bf(v[4] * inv); hm.y = f2bf(v[5] * inv);
    hm.z = f2bf(v[6] * inv); hm.w = f2bf(v[7] * inv);
    *(ushort4*)dst = lo;
    *(ushort4*)(dst + 4) = hm;
}

// ---------------------------------------------------------------------------
// K3: fused GEMM + epilogue. grid (64 n-tiles, 16 b, 2 branch), block 256.
// Mtile=512 (B panel read once), Ntile=64, BK=32, mfma_f32_32x32x16_bf16.
// out = sA[m]*x_fp32[m,s] + sB[m]*acc[m,s]
// ---------------------------------------------------------------------------
__global__ __launch_bounds__(256) void k3_gemm(
    const unsigned short* __restrict__ xbt, const unsigned short* __restrict__ xbc,
    const unsigned short* __restrict__ wswz,
    const float* __restrict__ xt, const float* __restrict__ xc,
    const float* __restrict__ sAt, const float* __restrict__ sBt,
    const float* __restrict__ attc,
    float* __restrict__ out)
{
    int nt = blockIdx.x, b = blockIdx.y, g = blockIdx.z;
    int t = threadIdx.x, lane = t & 63, w = t >> 6;
    int n0 = nt * 64;

    const unsigned short* xb = g ? xbt : xbc;   // B operand (cross input)
    const float* xref = g ? xc : xt;            // epilogue elementwise (fp32)
    const float* sA = g ? attc : sAt;
    const float* sB = g ? attc : sBt;

    __shared__ __align__(16) unsigned short As[16384];  // 32 KB, frag order
    __shared__ __align__(16) unsigned short Bs[2048];   //  4 KB, frag order

    f32x16 acc[4][2];
    #pragma unroll
    for (int r = 0; r < 4; ++r)
        #pragma unroll
        for (int c = 0; c < 2; ++c)
            #pragma unroll
            for (int e = 0; e < 16; ++e) acc[r][c][e] = 0.0f;

    // B staging: one 16B granule/thread: (ks=t>>7, cn=(t>>6)&1, lane)
    int bks = t >> 7, bcn = (t >> 6) & 1;
    const unsigned short* bgp = xb
        + ((size_t)b * SP + n0 + bcn * 32 + (lane & 31)) * CH
        + bks * 16 + (lane >> 5) * 8;
    unsigned short* bl = &Bs[t * 8];

    for (int kb = 0; kb < 16; ++kb) {
        __syncthreads();
        const unsigned short* ag = wswz + kb * 16384;   // pre-swizzled, coalesced
        #pragma unroll
        for (int i = 0; i < 8; ++i) {
            int gid = i * 256 + t;
            gld_lds16(ag + gid * 8, &As[gid * 8]);
        }
        gld_lds16(bgp + kb * 32, bl);
        __syncthreads();

        #pragma unroll
        for (int ks = 0; ks < 2; ++ks) {
            bf16x8 af[4], bfr[2];
            #pragma unroll
            for (int r = 0; r < 4; ++r)
                af[r] = *(const bf16x8*)&As[(((w * 4 + r) * 2 + ks) * 64 + lane) * 8];
            #pragma unroll
            for (int c = 0; c < 2; ++c)
                bfr[c] = *(const bf16x8*)&Bs[((ks * 2 + c) * 64 + lane) * 8];
            #pragma unroll
            for (int r = 0; r < 4; ++r)
                #pragma unroll
                for (int c = 0; c < 2; ++c)
                    acc[r][c] = __builtin_amdgcn_mfma_f32_32x32x16_bf16(
                        af[r], bfr[c], acc[r][c], 0, 0, 0);
        }
    }

    // epilogue: C/D layout row=(reg&3)+8*(reg>>2)+4*(lane>>5), col=lane&31
    size_t outg = (size_t)g * NELEM;
    int colbase = n0 + (lane & 31);
    int rowq = 4 * (lane >> 5);
    #pragma unroll
    for (int r = 0; r < 4; ++r) {
        #pragma unroll
        for (int c = 0; c < 2; ++c) {
            int col = colbase + c * 32;
            #pragma unroll
            for (int reg = 0; reg < 16; ++reg) {
                int m = w * 128 + r * 32 + (reg & 3) + 8 * (reg >> 2) + rowq;
                size_t idx = ((size_t)b * CH + m) * SP + col;
                float xv = xref[idx];
                float sav = sA[b * CH + m];
                float sbv = sB[b * CH + m];
                out[outg + idx] = sav * xv + sbv * acc[r][c][reg];
            }
        }
    }
}

// ---------------------------------------------------------------------------
extern "C" void kernel_launch(void* const* d_in, const int* in_sizes, int n_in,
                              void* d_out, int out_size, void* d_ws, size_t ws_size,
                              hipStream_t stream)
{
    const float* xt  = (const float*)d_in[0];
    const float* xc  = (const float*)d_in[1];
    const float* w1t = (const float*)d_in[2];
    const float* b1t = (const float*)d_in[3];
    const float* w2t = (const float*)d_in[4];
    const float* b2t = (const float*)d_in[5];
    const float* w1c = (const float*)d_in[6];
    const float* b1c = (const float*)d_in[7];
    const float* w2c = (const float*)d_in[8];
    const float* b2c = (const float*)d_in[9];
    const float* ca  = (const float*)d_in[10];
    float* out = (float*)d_out;
    char* ws = (char*)d_ws;

    unsigned short* xbt  = (unsigned short*)(ws);                    // 64 MiB
    unsigned short* xbc  = (unsigned short*)(ws + 67108864ull);      // 64 MiB
    unsigned short* wswz = (unsigned short*)(ws + 134217728ull);     // 512 KiB
    float* psum = (float*)(ws + 134742016ull);                       // 4 MiB
    float* sAt  = (float*)(ws + 138936320ull);                       // 32 KiB
    float* sBt  = (float*)(ws + 138969088ull);                       // 32 KiB
    float* attc = (float*)(ws + 139001856ull);                       // 32 KiB

    hipLaunchKernelGGL(k1_reduce_transpose, dim3(64, 8, 32), dim3(256), 0, stream,
                       xt, xc, xbt, xbc, psum);
    hipLaunchKernelGGL(k2_se, dim3(16, 2), dim3(512), 0, stream,
                       psum, w1t, b1t, w2t, b2t, w1c, b1c, w2c, b2c, sAt, sBt, attc);
    hipLaunchKernelGGL(k2_softmax, dim3(512), dim3(64), 0, stream, ca, wswz);
    hipLaunchKernelGGL(k3_gemm, dim3(64, 16, 2), dim3(256), 0, stream,
                       xbt, xbc, wswz, xt, xc, sAt, sBt, attc, out);
}

// Round 2
// 712.858 us; speedup vs baseline: 1.0048x; 1.0048x over previous
//
#include <hip/hip_runtime.h>

#define NBATCH 16
#define CH 512
#define HID 32
#define KTOP 153
#define SP 4096
#define NELEM (NBATCH*CH*SP)   // 33554432

typedef __bf16 bf16x8 __attribute__((ext_vector_type(8)));
typedef float f32x16 __attribute__((ext_vector_type(16)));

__device__ __forceinline__ unsigned short f2bf(float f) {
    union { float f; unsigned u; } v; v.f = f;
    unsigned r = v.u + 0x7FFFu + ((v.u >> 16) & 1u);   // RNE
    return (unsigned short)(r >> 16);
}

// ---------------------------------------------------------------------------
// K1: per-(b,ch) spatial partial sums (fp32, deterministic) + transpose x to
// channel-major bf16 xb[b][s][k]. LDS fp32 tile (pad 73 -> <=2-way = free)
// replaces the 96-swizzle butterfly of round 0.
// grid (64 s-blocks, 8 ch-blocks, 32 = b*2+branch), block 256.
// ---------------------------------------------------------------------------
__global__ __launch_bounds__(256) void k1_reduce_transpose(
    const float* __restrict__ xt, const float* __restrict__ xc,
    unsigned short* __restrict__ xbt, unsigned short* __restrict__ xbc,
    float* __restrict__ psum)
{
    int sb = blockIdx.x, chb = blockIdx.y, bz = blockIdx.z;
    int b = bz >> 1, br = bz & 1;
    const float* x = br ? xc : xt;
    unsigned short* xb = br ? xbc : xbt;
    int t = threadIdx.x, lane = t & 63, w = t >> 6;
    int s0 = sb * 64, ch0 = chb * 64;

    // G[ch][s], leading dim 73: cols 0..63 = data, cols 64..67 = partials
    __shared__ float G[64 * 73];

    const float* xbase = x + (size_t)b * CH * SP + s0 + lane;
    #pragma unroll
    for (int it = 0; it < 4; ++it)
        #pragma unroll
        for (int i = 0; i < 4; ++i) {
            int chl = w * 4 + i + 16 * it;
            G[chl * 73 + lane] = xbase[(size_t)(ch0 + chl) * SP];
        }
    __syncthreads();

    // per-channel partial sums over 16 spatial each (fp32, deterministic)
    {
        int chl = t & 63, q = t >> 6;
        const float* row = &G[chl * 73 + q * 16];
        float s = 0.f;
        #pragma unroll
        for (int i = 0; i < 16; ++i) s += row[i];
        G[chl * 73 + 64 + q] = s;
    }
    __syncthreads();

    if (t < 64) {
        const float* p = &G[t * 73 + 64];
        float s = p[0] + p[1] + p[2] + p[3];
        psum[((size_t)sb * 32 + (br * 16 + b)) * CH + ch0 + t] = s;
    }

    // transpose-out: xb[b][s0+s][ch0..63] as bf16 ushort4 chunks, coalesced
    size_t orow = (size_t)b * SP + s0;
    #pragma unroll
    for (int q = 0; q < 4; ++q) {
        int gid = q * 256 + t;
        int sl = gid >> 4;
        int c4 = (gid & 15) * 4;
        ushort4 d;
        d.x = f2bf(G[(c4 + 0) * 73 + sl]);
        d.y = f2bf(G[(c4 + 1) * 73 + sl]);
        d.z = f2bf(G[(c4 + 2) * 73 + sl]);
        d.w = f2bf(G[(c4 + 3) * 73 + sl]);
        *(ushort4*)&xb[(orow + sl) * CH + ch0 + c4] = d;
    }
}

// ---------------------------------------------------------------------------
// K2a: finish means (coalesced psum layout), SE MLP (fp32, hidden layer
// parallelized over all 512 threads), sigmoid, exact top-153 mask.
// grid (16 b, 2 branch), block 512.
// ---------------------------------------------------------------------------
__global__ __launch_bounds__(512) void k2_se(
    const float* __restrict__ psum,
    const float* __restrict__ w1t, const float* __restrict__ b1t,
    const float* __restrict__ w2t, const float* __restrict__ b2t,
    const float* __restrict__ w1c, const float* __restrict__ b1c,
    const float* __restrict__ w2c, const float* __restrict__ b2c,
    float* __restrict__ sAt, float* __restrict__ sBt, float* __restrict__ attc)
{
    int b = blockIdx.x, br = blockIdx.y;
    int bb = br * 16 + b;
    int t = threadIdx.x;
    __shared__ float satt[512];
    __shared__ float ph[16][33];
    __shared__ float sh[32];
    __shared__ float sval[512];

    float s = 0.f;
    #pragma unroll
    for (int j = 0; j < 64; ++j) s += psum[((size_t)j * 32 + bb) * CH + t];
    satt[t] = s * (1.0f / 4096.0f);
    __syncthreads();

    const float* w1 = br ? w1c : w1t; const float* b1 = br ? b1c : b1t;
    const float* w2 = br ? w2c : w2t; const float* b2 = br ? b2c : b2t;

    // hidden: h[j] = sum_i satt[i]*w1[i][j]; 16 segments x 32 j
    {
        int j = t & 31, seg = t >> 5;
        float hp = 0.f;
        #pragma unroll
        for (int i = 0; i < 32; ++i)
            hp += satt[seg * 32 + i] * w1[(seg * 32 + i) * HID + j];
        ph[seg][j] = hp;
    }
    __syncthreads();
    if (t < HID) {
        float h = b1[t];
        #pragma unroll
        for (int sgi = 0; sgi < 16; ++sgi) h += ph[sgi][t];
        sh[t] = fmaxf(h, 0.0f);
    }
    __syncthreads();

    float z = b2[t];
    #pragma unroll
    for (int j = 0; j < HID; ++j) z += sh[j] * w2[j * CH + t];
    float a = 1.0f / (1.0f + expf(-z));

    if (br == 0) {
        sval[t] = a;
        __syncthreads();
        int cnt = 0;
        for (int j = 0; j < CH; ++j) {
            float o = sval[j];
            cnt += (o > a) || (o == a && j < t);   // matches top_k tie order
        }
        sAt[b * CH + t] = a;
        sBt[b * CH + t] = (cnt < KTOP) ? 1.0f : 0.0f;
    } else {
        attc[b * CH + t] = a;
    }
}

// ---------------------------------------------------------------------------
// K2b: softmax rows of cross_att -> bf16 W, PRE-SWIZZLED to MFMA A-fragment
// granule order: granule(m,k8): pos = ((kb*16 + (m>>5))*2 + ks)*64 + hi*32 + (m&31)
// grid 512 rows, block 64.
// ---------------------------------------------------------------------------
__global__ __launch_bounds__(64) void k2_softmax(
    const float* __restrict__ ca, unsigned short* __restrict__ wswz)
{
    int trow = blockIdx.x;
    int lane = threadIdx.x;
    const float* row = ca + (size_t)trow * CH;
    float v[8];
    #pragma unroll
    for (int i = 0; i < 8; ++i) v[i] = row[lane * 8 + i];
    float m = v[0];
    #pragma unroll
    for (int i = 1; i < 8; ++i) m = fmaxf(m, v[i]);
    #pragma unroll
    for (int off = 32; off; off >>= 1) m = fmaxf(m, __shfl_xor(m, off, 64));
    float s = 0.f;
    #pragma unroll
    for (int i = 0; i < 8; ++i) { v[i] = expf(v[i] - m); s += v[i]; }
    #pragma unroll
    for (int off = 32; off; off >>= 1) s += __shfl_xor(s, off, 64);
    float inv = 1.0f / s;

    int k = lane * 8;
    int kb = k >> 5, ks = (k >> 4) & 1, hi = (k >> 3) & 1;
    int p = ((kb * 16 + (trow >> 5)) * 2 + ks) * 64 + hi * 32 + (trow & 31);
    unsigned short* dst = wswz + (size_t)p * 8;
    ushort4 lo, hm;
    lo.x = f2bf(v[0] * inv); lo.y = f2bf(v[1] * inv);
    lo.z = f2bf(v[2] * inv); lo.w = f2bf(v[3] * inv);
    hm.x = f2bf(v[4] * inv); hm.y = f2bf(v[5] * inv);
    hm.z = f2bf(v[6] * inv); hm.w = f2bf(v[7] * inv);
    *(ushort4*)dst = lo;
    *(ushort4*)(dst + 4) = hm;
}

// ---------------------------------------------------------------------------
// K3: fused GEMM + epilogue. ZERO LDS, ZERO barriers: both operands are
// pre-swizzled so each lane's fragment is one contiguous 16B global granule.
// Double-buffered fragment registers give 1-iteration lookahead; no vmcnt(0)
// drains. grid (64 n-tiles, 16 b, 2 branch), block 256.
// Mtile=512 (B panel read once), Ntile=64, BK=32, mfma_f32_32x32x16_bf16.
// ---------------------------------------------------------------------------
__global__ __launch_bounds__(256, 2) void k3_gemm(
    const unsigned short* __restrict__ xbt, const unsigned short* __restrict__ xbc,
    const unsigned short* __restrict__ wswz,
    const float* __restrict__ xt, const float* __restrict__ xc,
    const float* __restrict__ sAt, const float* __restrict__ sBt,
    const float* __restrict__ attc,
    float* __restrict__ out)
{
    int nt = blockIdx.x, b = blockIdx.y, g = blockIdx.z;
    int t = threadIdx.x, lane = t & 63, w = t >> 6;
    int n0 = nt * 64;

    const unsigned short* xb = g ? xbt : xbc;   // B operand (cross input)
    const float* xref = g ? xc : xt;            // epilogue elementwise (fp32)
    const float* sA = g ? attc : sAt;
    const float* sB = g ? attc : sBt;

    f32x16 acc[4][2];
    #pragma unroll
    for (int r = 0; r < 4; ++r)
        #pragma unroll
        for (int c = 0; c < 2; ++c)
            #pragma unroll
            for (int e = 0; e < 16; ++e) acc[r][c][e] = 0.0f;

    // A granule for (kb,r,ks): wswz + (((kb*16 + (w*4+r))*2 + ks)*64 + lane)*8
    const unsigned short* abase = wswz + ((size_t)(w * 4 * 2 * 64 + lane)) * 8;
    // B granule for (kb,c,ks): xb[(b*SP+n0+c*32+(lane&31))*CH + kb*32+ks*16+(lane>>5)*8]
    const unsigned short* bbase = xb + ((size_t)b * SP + n0 + (lane & 31)) * CH
                                     + (lane >> 5) * 8;

    bf16x8 afr[2][8], bfr[2][4];

    #pragma unroll
    for (int r = 0; r < 4; ++r)
        #pragma unroll
        for (int ks = 0; ks < 2; ++ks)
            afr[0][r * 2 + ks] = *(const bf16x8*)(abase + r * 1024 + ks * 512);
    #pragma unroll
    for (int c = 0; c < 2; ++c)
        #pragma unroll
        for (int ks = 0; ks < 2; ++ks)
            bfr[0][c * 2 + ks] = *(const bf16x8*)(bbase + c * 16384 + ks * 16);

    #pragma unroll
    for (int kb = 0; kb < 16; ++kb) {
        int cur = kb & 1, nxt = cur ^ 1;
        if (kb < 15) {
            #pragma unroll
            for (int r = 0; r < 4; ++r)
                #pragma unroll
                for (int ks = 0; ks < 2; ++ks)
                    afr[nxt][r * 2 + ks] =
                        *(const bf16x8*)(abase + (kb + 1) * 16384 + r * 1024 + ks * 512);
            #pragma unroll
            for (int c = 0; c < 2; ++c)
                #pragma unroll
                for (int ks = 0; ks < 2; ++ks)
                    bfr[nxt][c * 2 + ks] =
                        *(const bf16x8*)(bbase + c * 16384 + (kb + 1) * 32 + ks * 16);
        }
        #pragma unroll
        for (int ks = 0; ks < 2; ++ks)
            #pragma unroll
            for (int r = 0; r < 4; ++r)
                #pragma unroll
                for (int c = 0; c < 2; ++c)
                    acc[r][c] = __builtin_amdgcn_mfma_f32_32x32x16_bf16(
                        afr[cur][r * 2 + ks], bfr[cur][c * 2 + ks], acc[r][c], 0, 0, 0);
    }

    // epilogue: C/D layout row=(reg&3)+8*(reg>>2)+4*(lane>>5), col=lane&31
    size_t outg = (size_t)g * NELEM;
    int colbase = n0 + (lane & 31);
    int rowq = 4 * (lane >> 5);
    #pragma unroll
    for (int r = 0; r < 4; ++r) {
        #pragma unroll
        for (int reg = 0; reg < 16; ++reg) {
            int m = w * 128 + r * 32 + (reg & 3) + 8 * (reg >> 2) + rowq;
            float sav = sA[b * CH + m];
            float sbv = sB[b * CH + m];
            #pragma unroll
            for (int c = 0; c < 2; ++c) {
                size_t idx = ((size_t)b * CH + m) * SP + colbase + c * 32;
                out[outg + idx] = sav * xref[idx] + sbv * acc[r][c][reg];
            }
        }
    }
}

// ---------------------------------------------------------------------------
extern "C" void kernel_launch(void* const* d_in, const int* in_sizes, int n_in,
                              void* d_out, int out_size, void* d_ws, size_t ws_size,
                              hipStream_t stream)
{
    const float* xt  = (const float*)d_in[0];
    const float* xc  = (const float*)d_in[1];
    const float* w1t = (const float*)d_in[2];
    const float* b1t = (const float*)d_in[3];
    const float* w2t = (const float*)d_in[4];
    const float* b2t = (const float*)d_in[5];
    const float* w1c = (const float*)d_in[6];
    const float* b1c = (const float*)d_in[7];
    const float* w2c = (const float*)d_in[8];
    const float* b2c = (const float*)d_in[9];
    const float* ca  = (const float*)d_in[10];
    float* out = (float*)d_out;
    char* ws = (char*)d_ws;

    unsigned short* xbt  = (unsigned short*)(ws);                    // 64 MiB
    unsigned short* xbc  = (unsigned short*)(ws + 67108864ull);      // 64 MiB
    unsigned short* wswz = (unsigned short*)(ws + 134217728ull);     // 512 KiB
    float* psum = (float*)(ws + 134742016ull);                       // 4 MiB
    float* sAt  = (float*)(ws + 138936320ull);                       // 32 KiB
    float* sBt  = (float*)(ws + 138969088ull);                       // 32 KiB
    float* attc = (float*)(ws + 139001856ull);                       // 32 KiB

    hipLaunchKernelGGL(k1_reduce_transpose, dim3(64, 8, 32), dim3(256), 0, stream,
                       xt, xc, xbt, xbc, psum);
    hipLaunchKernelGGL(k2_se, dim3(16, 2), dim3(512), 0, stream,
                       psum, w1t, b1t, w2t, b2t, w1c, b1c, w2c, b2c, sAt, sBt, attc);
    hipLaunchKernelGGL(k2_softmax, dim3(512), dim3(64), 0, stream, ca, wswz);
    hipLaunchKernelGGL(k3_gemm, dim3(64, 16, 2), dim3(256), 0, stream,
                       xbt, xbc, wswz, xt, xc, sAt, sBt, attc, out);
}